// Round 1
// baseline (1816.904 us; speedup 1.0000x reference)
//
#include <hip/hip_runtime.h>

#define NBOX 300000
#define NFEAT 85
#define NCLS 80
#define NBUCK 4096
#define M_TARGET 7680u
#define CMAX 8192
#define MAXKEEP 1000

__device__ __forceinline__ int bucket_of(float s) {
    int b = (int)((s - 0.3f) * (4096.0f / 0.7f));
    if (b < 0) b = 0;
    if (b > NBUCK - 1) b = NBUCK - 1;
    return b;
}

__device__ __forceinline__ bool sup_iou(float by1, float bx1, float by2, float bx2, float ba,
                                        float y1, float x1, float y2, float x2, float area) {
    float iy1 = fmaxf(by1, y1), ix1 = fmaxf(bx1, x1);
    float iy2 = fminf(by2, y2), ix2 = fminf(bx2, x2);
    float inter = fmaxf(iy2 - iy1, 0.0f) * fmaxf(ix2 - ix1, 0.0f);
    float uni = ba + area - inter;
    float iou = (uni > 0.0f) ? inter / uni : 0.0f;
    return iou > 0.5f;
}

__global__ void k_init(unsigned* __restrict__ hist, int* __restrict__ meta) {
    int i = blockIdx.x * blockDim.x + threadIdx.x;
    if (i < NBUCK) hist[i] = 0u;
    if (i < 8) meta[i] = 0;
}

__global__ void k_scores(const float* __restrict__ in, float* __restrict__ scores,
                         unsigned* __restrict__ hist) {
    int i = blockIdx.x * blockDim.x + threadIdx.x;
    if (i >= NBOX) return;
    const float* row = in + (long long)i * NFEAT;
    float conf = row[4];
    float best = -1.0f;
    #pragma unroll
    for (int j = 0; j < NCLS; ++j) best = fmaxf(best, conf * row[5 + j]);
    scores[i] = best;
    if (best >= 0.3f) atomicAdd(&hist[bucket_of(best)], 1u);
}

__global__ void __launch_bounds__(1024) k_thresh(const unsigned* __restrict__ hist,
                                                 int* __restrict__ meta) {
    __shared__ unsigned chunk[1024];
    int t = threadIdx.x;
    unsigned h[4];
    unsigned s = 0;
    #pragma unroll
    for (int j = 0; j < 4; ++j) { h[j] = hist[t * 4 + j]; s += h[j]; }
    chunk[t] = s;
    __syncthreads();
    for (int off = 1; off < 1024; off <<= 1) {
        unsigned add = (t + off < 1024) ? chunk[t + off] : 0u;
        __syncthreads();
        chunk[t] += add;
        __syncthreads();
    }
    unsigned after = (t + 1 < 1024) ? chunk[t + 1] : 0u;
    unsigned suf[5];
    suf[4] = after;
    #pragma unroll
    for (int j = 3; j >= 0; --j) suf[j] = suf[j + 1] + h[j];
    #pragma unroll
    for (int j = 0; j < 4; ++j) {
        if (suf[j] >= M_TARGET && suf[j + 1] < M_TARGET) meta[1] = t * 4 + j;
    }
    if (t == 0 && chunk[0] < M_TARGET) meta[1] = 0;
}

__global__ void k_compact(const float* __restrict__ scores, int* __restrict__ meta,
                          unsigned long long* __restrict__ keys) {
    int i = blockIdx.x * blockDim.x + threadIdx.x;
    if (i >= NBOX) return;
    float s = scores[i];
    if (s < 0.3f) return;
    if (bucket_of(s) < meta[1]) return;
    int pos = atomicAdd(&meta[0], 1);
    if (pos < CMAX) {
        keys[pos] = ((unsigned long long)__float_as_uint(s) << 32) |
                    (unsigned long long)(0xFFFFFFFFu - (unsigned)i);
    }
}

__global__ void __launch_bounds__(1024) k_sortnms(const float* __restrict__ in,
        unsigned long long* __restrict__ gkeys, int* __restrict__ meta,
        int* __restrict__ kept) {
    __shared__ union {
        unsigned long long keys[CMAX];               // 64 KB, sort phase
        struct { float4 kb4[1024]; int s_kept; } n;  // NMS phase (aliases keys)
    } sh;
    int t = threadIdx.x;
    int count = meta[0];
    if (count > CMAX) count = CMAX;

    // ---- load + bitonic sort (descending: score desc, idx asc) ----
    for (int i = t; i < CMAX; i += 1024) sh.keys[i] = (i < count) ? gkeys[i] : 0ull;
    __syncthreads();
    for (int k = 2; k <= CMAX; k <<= 1) {
        for (int j = k >> 1; j > 0; j >>= 1) {
            for (int i = t; i < CMAX; i += 1024) {
                int ixj = i ^ j;
                if (ixj > i) {
                    unsigned long long a = sh.keys[i], b = sh.keys[ixj];
                    bool up = ((i & k) == 0);
                    if (up ? (a < b) : (a > b)) { sh.keys[i] = b; sh.keys[ixj] = a; }
                }
            }
            __syncthreads();
        }
    }
    for (int i = t; i < CMAX; i += 1024) gkeys[i] = sh.keys[i];
    __syncthreads();
    if (t == 0) sh.n.s_kept = 0;
    __syncthreads();

    // ---- greedy NMS over sorted candidates ----
    int lane = t & 63, wid = t >> 6;
    for (int pos = 0; pos < count; pos += 1024) {
        if (sh.n.s_kept >= MAXKEEP) break;
        int c = pos + t;
        bool alive = (c < count);
        float y1 = 0.f, x1 = 0.f, y2 = 0.f, x2 = 0.f, area = 0.f;
        int bi = 0;
        if (alive) {
            unsigned long long key = gkeys[c];
            bi = (int)(0xFFFFFFFFu - (unsigned)(key & 0xFFFFFFFFull));
            const float* r = in + (long long)bi * NFEAT;
            y1 = r[0]; x1 = r[1]; y2 = r[2]; x2 = r[3];
            area = (y2 - y1) * (x2 - x1);
        }
        int kc0 = sh.n.s_kept;  // uniform snapshot (post-barrier)
        // prefilter vs all keeps existing before this batch
        {
            int lim = alive ? kc0 : 0;
            for (int k2 = 0; k2 < lim && alive; ++k2) {
                float4 b = sh.n.kb4[k2];
                float ba = (b.z - b.x) * (b.w - b.y);
                if (sup_iou(b.x, b.y, b.z, b.w, ba, y1, x1, y2, x2, area)) alive = false;
            }
        }
        __syncthreads();
        // wave-sequential intra-batch resolution
        for (int w = 0; w < 16; ++w) {
            if (wid == w) {
                int kc2 = sh.n.s_kept;
                for (int k2 = kc0; k2 < kc2 && alive; ++k2) {  // keeps added by earlier waves
                    float4 b = sh.n.kb4[k2];
                    float ba = (b.z - b.x) * (b.w - b.y);
                    if (sup_iou(b.x, b.y, b.z, b.w, ba, y1, x1, y2, x2, area)) alive = false;
                }
                unsigned long long aliveM = __ballot(alive ? 1 : 0);
                unsigned long long col = 0ull;  // lane i: bitmask of lanes i suppresses
                for (int i2 = 0; i2 < 64; ++i2) {
                    if (!((aliveM >> i2) & 1ull)) continue;  // uniform skip
                    float by1 = __shfl(y1, i2), bx1 = __shfl(x1, i2);
                    float by2 = __shfl(y2, i2), bx2 = __shfl(x2, i2);
                    float ba = (by2 - by1) * (bx2 - bx1);
                    bool s = (lane > i2) &&
                             sup_iou(by1, bx1, by2, bx2, ba, y1, x1, y2, x2, area);
                    unsigned long long bm = __ballot(s ? 1 : 0);
                    if (lane == i2) col = bm;
                }
                // exact serial greedy over the 64-bit masks (uniform in wave)
                unsigned long long remaining = aliveM, keptM = 0ull;
                while (remaining) {
                    int i2 = __ffsll((unsigned long long)remaining) - 1;
                    unsigned long long ci = __shfl(col, i2);
                    keptM |= (1ull << i2);
                    remaining &= ~(1ull << i2);
                    remaining &= ~ci;
                }
                int base = kc2;
                int nk = __popcll(keptM);
                int take = min(nk, MAXKEEP - base);
                if ((keptM >> lane) & 1ull) {
                    int rank = __popcll(keptM & ((1ull << lane) - 1ull));
                    if (rank < take) {
                        int p = base + rank;
                        sh.n.kb4[p] = make_float4(y1, x1, y2, x2);
                        kept[p] = bi;
                    }
                }
                if (lane == 0) sh.n.s_kept = base + take;
            }
            __syncthreads();
            if (sh.n.s_kept >= MAXKEEP) break;
        }
    }
    __syncthreads();
    if (t == 0) meta[2] = sh.n.s_kept;
}

__global__ void k_output(const float* __restrict__ in, const int* __restrict__ meta,
                         const int* __restrict__ kept, float* __restrict__ out) {
    int r = blockIdx.x * blockDim.x + threadIdx.x;
    if (r >= MAXKEEP) return;
    int kc = meta[2];
    float o0 = 0.f, o1 = 0.f, o2 = 0.f, o3 = 0.f, o4 = 0.f, o5 = 0.f;
    if (r < kc) {
        int bi = kept[r];
        const float* row = in + (long long)bi * NFEAT;
        o0 = row[0]; o1 = row[1]; o2 = row[2]; o3 = row[3];
        float conf = row[4];
        float best = -1.0f;
        int cls = 0;
        for (int j = 0; j < NCLS; ++j) {
            float s = conf * row[5 + j];
            if (s > best) { best = s; cls = j; }  // strict > : first occurrence, matches jnp.argmax
        }
        o4 = (float)cls; o5 = best;
    }
    float* orow = out + r * 6;
    orow[0] = o0; orow[1] = o1; orow[2] = o2;
    orow[3] = o3; orow[4] = o4; orow[5] = o5;
}

extern "C" void kernel_launch(void* const* d_in, const int* in_sizes, int n_in,
                              void* d_out, int out_size, void* d_ws, size_t ws_size,
                              hipStream_t stream) {
    const float* in = (const float*)d_in[0];
    float* out = (float*)d_out;
    char* ws = (char*)d_ws;
    // ws layout (bytes):
    //   [0, 1200000)            scores  f32[300000]
    //   [1200000, 1216384)      hist    u32[4096]
    //   [1216384, 1216416)      meta    i32[8]   {0:cand counter, 1:bstar, 2:kept count}
    //   [1216416, 1281952)      keys    u64[8192]
    //   [1281952, 1286048)      kept    i32[1024]
    float* scores = (float*)(ws);
    unsigned* hist = (unsigned*)(ws + 1200000);
    int* meta = (int*)(ws + 1216384);
    unsigned long long* keys = (unsigned long long*)(ws + 1216416);
    int* kept = (int*)(ws + 1216416 + (size_t)CMAX * 8);

    k_init<<<dim3(16), dim3(256), 0, stream>>>(hist, meta);
    k_scores<<<dim3((NBOX + 255) / 256), dim3(256), 0, stream>>>(in, scores, hist);
    k_thresh<<<dim3(1), dim3(1024), 0, stream>>>(hist, meta);
    k_compact<<<dim3((NBOX + 255) / 256), dim3(256), 0, stream>>>(scores, meta, keys);
    k_sortnms<<<dim3(1), dim3(1024), 0, stream>>>(in, keys, meta, kept);
    k_output<<<dim3((MAXKEEP + 255) / 256), dim3(256), 0, stream>>>(in, meta, kept, out);
}

// Round 2
// 407.988 us; speedup vs baseline: 4.4533x; 4.4533x over previous
//
#include <hip/hip_runtime.h>

#define NBOX 300000
#define NFEAT 85
#define NCLS 80
#define NBUCK 4096
#define M_TARGET 7680u
#define CMAX 8192
#define W64 (CMAX / 64)   // 128 mask words per candidate row
#define MAXKEEP 1000

typedef unsigned long long u64;

__device__ __forceinline__ int bucket_of(float s) {
    int b = (int)((s - 0.3f) * (4096.0f / 0.7f));
    if (b < 0) b = 0;
    if (b > NBUCK - 1) b = NBUCK - 1;
    return b;
}

__device__ __forceinline__ bool sup_iou(float by1, float bx1, float by2, float bx2, float ba,
                                        float y1, float x1, float y2, float x2, float area) {
    float iy1 = fmaxf(by1, y1), ix1 = fmaxf(bx1, x1);
    float iy2 = fminf(by2, y2), ix2 = fminf(bx2, x2);
    float inter = fmaxf(iy2 - iy1, 0.0f) * fmaxf(ix2 - ix1, 0.0f);
    float uni = ba + area - inter;
    float iou = (uni > 0.0f) ? inter / uni : 0.0f;
    return iou > 0.5f;
}

__global__ void k_init(unsigned* __restrict__ hist, int* __restrict__ meta) {
    int i = blockIdx.x * blockDim.x + threadIdx.x;
    if (i < NBUCK) hist[i] = 0u;
    if (i < 8) meta[i] = 0;
}

__global__ void k_scores(const float* __restrict__ in, float* __restrict__ scores,
                         unsigned* __restrict__ hist) {
    int i = blockIdx.x * blockDim.x + threadIdx.x;
    if (i >= NBOX) return;
    const float* row = in + (long long)i * NFEAT;
    float conf = row[4];
    float best = -1.0f;
    #pragma unroll
    for (int j = 0; j < NCLS; ++j) best = fmaxf(best, conf * row[5 + j]);
    scores[i] = best;
    if (best >= 0.3f) atomicAdd(&hist[bucket_of(best)], 1u);
}

__global__ void __launch_bounds__(1024) k_thresh(const unsigned* __restrict__ hist,
                                                 int* __restrict__ meta) {
    __shared__ unsigned chunk[1024];
    int t = threadIdx.x;
    unsigned h[4];
    unsigned s = 0;
    #pragma unroll
    for (int j = 0; j < 4; ++j) { h[j] = hist[t * 4 + j]; s += h[j]; }
    chunk[t] = s;
    __syncthreads();
    for (int off = 1; off < 1024; off <<= 1) {
        unsigned add = (t + off < 1024) ? chunk[t + off] : 0u;
        __syncthreads();
        chunk[t] += add;
        __syncthreads();
    }
    unsigned after = (t + 1 < 1024) ? chunk[t + 1] : 0u;
    unsigned suf[5];
    suf[4] = after;
    #pragma unroll
    for (int j = 3; j >= 0; --j) suf[j] = suf[j + 1] + h[j];
    #pragma unroll
    for (int j = 0; j < 4; ++j) {
        if (suf[j] >= M_TARGET && suf[j + 1] < M_TARGET) meta[1] = t * 4 + j;
    }
    if (t == 0 && chunk[0] < M_TARGET) meta[1] = 0;
}

__global__ void k_compact(const float* __restrict__ scores, int* __restrict__ meta,
                          u64* __restrict__ keys) {
    int i = blockIdx.x * blockDim.x + threadIdx.x;
    if (i >= NBOX) return;
    float s = scores[i];
    if (s < 0.3f) return;
    if (bucket_of(s) < meta[1]) return;
    int pos = atomicAdd(&meta[0], 1);
    if (pos < CMAX) {
        keys[pos] = ((u64)__float_as_uint(s) << 32) |
                    (u64)(0xFFFFFFFFu - (unsigned)i);
    }
}

// Single-block bitonic sort of CMAX u64 keys, descending (score desc, idx asc).
__global__ void __launch_bounds__(1024) k_sort(u64* __restrict__ gkeys,
                                               const int* __restrict__ meta) {
    __shared__ u64 keys[CMAX];  // 64 KB
    int t = threadIdx.x;
    int count = meta[0];
    if (count > CMAX) count = CMAX;
    for (int i = t; i < CMAX; i += 1024) keys[i] = (i < count) ? gkeys[i] : 0ull;
    __syncthreads();
    for (int k = 2; k <= CMAX; k <<= 1) {
        for (int j = k >> 1; j > 0; j >>= 1) {
            for (int i = t; i < CMAX; i += 1024) {
                int ixj = i ^ j;
                if (ixj > i) {
                    u64 a = keys[i], b = keys[ixj];
                    bool up = ((i & k) == 0);
                    if (up ? (a < b) : (a > b)) { keys[i] = b; keys[ixj] = a; }
                }
            }
            __syncthreads();
        }
    }
    for (int i = t; i < CMAX; i += 1024) gkeys[i] = keys[i];
}

// Pairwise suppression masks: masks[i][w] bit b = (j = w*64+b) > i && IoU(i,j) > 0.5.
// Only upper-triangle words (tj >= ti) are written; sweep never reads the rest.
__global__ void __launch_bounds__(256) k_masks(const float* __restrict__ in,
        const u64* __restrict__ gkeys, const int* __restrict__ meta,
        u64* __restrict__ masks) {
    int ti = blockIdx.y, tj = blockIdx.x;
    if (tj < ti) return;
    int count = meta[0];
    if (count > CMAX) count = CMAX;
    __shared__ float4 rb[64];
    int t = threadIdx.x;
    if (t < 64) {
        int r = ti * 64 + t;
        float4 b = make_float4(0.f, 0.f, 0.f, 0.f);
        if (r < count) {
            u64 key = gkeys[r];
            int bi = (int)(0xFFFFFFFFu - (unsigned)(key & 0xFFFFFFFFull));
            const float* p = in + (long long)bi * NFEAT;
            b = make_float4(p[0], p[1], p[2], p[3]);  // y1,x1,y2,x2
        }
        rb[t] = b;
    }
    int lane = t & 63, wid = t >> 6;
    int cj = tj * 64 + lane;
    float cy1 = 0.f, cx1 = 0.f, cy2 = 0.f, cx2 = 0.f, carea = 0.f;
    bool cvalid = (cj < count);
    if (cvalid) {
        u64 key = gkeys[cj];
        int bi = (int)(0xFFFFFFFFu - (unsigned)(key & 0xFFFFFFFFull));
        const float* p = in + (long long)bi * NFEAT;
        cy1 = p[0]; cx1 = p[1]; cy2 = p[2]; cx2 = p[3];
        carea = (cy2 - cy1) * (cx2 - cx1);
    }
    __syncthreads();
    #pragma unroll
    for (int r = 0; r < 16; ++r) {
        int i = ti * 64 + wid * 16 + r;
        float4 b = rb[wid * 16 + r];
        float ba = (b.z - b.x) * (b.w - b.y);
        bool s = cvalid && (cj > i) && (i < count) &&
                 sup_iou(b.x, b.y, b.z, b.w, ba, cy1, cx1, cy2, cx2, carea);
        u64 word = __ballot(s ? 1 : 0);
        if (lane == 0) masks[(size_t)i * W64 + tj] = word;
    }
}

// Serial greedy sweep over the mask matrix: one wave, removed-mask wave-held
// (lane l owns words l and l+64), 8-deep register prefetch of mask rows.
__global__ void __launch_bounds__(64) k_sweep(const u64* __restrict__ masks,
        int* __restrict__ meta, int* __restrict__ keptpos) {
    int lane = threadIdx.x;
    int count = meta[0];
    if (count > CMAX) count = CMAX;
    u64 R0 = 0ull, R1 = 0ull;
    u64 a0[8], a1[8], b0[8], b1[8];
    #pragma unroll
    for (int k = 0; k < 8; ++k) {
        int i = (k < CMAX) ? k : CMAX - 1;
        const u64* row = masks + (size_t)i * W64;
        a0[k] = row[lane]; a1[k] = row[lane + 64];
    }
    int nk = 0;
    for (int base = 0; base < count && nk < MAXKEEP; base += 8) {
        #pragma unroll
        for (int k = 0; k < 8; ++k) {
            int i = base + 8 + k;
            if (i > CMAX - 1) i = CMAX - 1;
            const u64* row = masks + (size_t)i * W64;
            b0[k] = row[lane]; b1[k] = row[lane + 64];
        }
        #pragma unroll
        for (int k = 0; k < 8; ++k) {
            int i = base + k;
            if (i >= count || nk >= MAXKEEP) break;
            int i0 = i >> 6, b = i & 63;
            u64 rw = (i0 < 64) ? R0 : R1;
            u64 bal = __ballot((((rw >> b) & 1ull) != 0ull) ? 1 : 0);
            bool removed = (bal >> (i0 & 63)) & 1ull;
            if (!removed) {
                u64 m0 = (lane >= i0) ? a0[k] : 0ull;
                u64 m1 = ((lane + 64) >= i0) ? a1[k] : 0ull;
                R0 |= m0; R1 |= m1;
                if (lane == 0) keptpos[nk] = i;
                nk++;
            }
        }
        #pragma unroll
        for (int k = 0; k < 8; ++k) { a0[k] = b0[k]; a1[k] = b1[k]; }
    }
    if (lane == 0) meta[2] = nk;
}

__global__ void k_output(const float* __restrict__ in, const u64* __restrict__ gkeys,
                         const int* __restrict__ meta, const int* __restrict__ keptpos,
                         float* __restrict__ out) {
    int r = blockIdx.x * blockDim.x + threadIdx.x;
    if (r >= MAXKEEP) return;
    int kc = meta[2];
    float o0 = 0.f, o1 = 0.f, o2 = 0.f, o3 = 0.f, o4 = 0.f, o5 = 0.f;
    if (r < kc) {
        int pos = keptpos[r];
        u64 key = gkeys[pos];
        int bi = (int)(0xFFFFFFFFu - (unsigned)(key & 0xFFFFFFFFull));
        const float* row = in + (long long)bi * NFEAT;
        o0 = row[0]; o1 = row[1]; o2 = row[2]; o3 = row[3];
        float conf = row[4];
        float best = -1.0f;
        int cls = 0;
        for (int j = 0; j < NCLS; ++j) {
            float s = conf * row[5 + j];
            if (s > best) { best = s; cls = j; }  // strict > : first occurrence, matches jnp.argmax
        }
        o4 = (float)cls; o5 = best;
    }
    float* orow = out + r * 6;
    orow[0] = o0; orow[1] = o1; orow[2] = o2;
    orow[3] = o3; orow[4] = o4; orow[5] = o5;
}

extern "C" void kernel_launch(void* const* d_in, const int* in_sizes, int n_in,
                              void* d_out, int out_size, void* d_ws, size_t ws_size,
                              hipStream_t stream) {
    const float* in = (const float*)d_in[0];
    float* out = (float*)d_out;
    char* ws = (char*)d_ws;
    // ws layout (bytes):
    //   [0, 1200000)            scores   f32[300000]
    //   [1200000, 1216384)      hist     u32[4096]
    //   [1216384, 1216416)      meta     i32[8]  {0:cand count, 1:bucket thr, 2:kept count}
    //   [1216416, 1281952)      keys     u64[8192]
    //   [1281952, 1286048)      keptpos  i32[1024]
    //   [1286144, 9674752)      masks    u64[8192*128]  (8 MB)
    float* scores = (float*)(ws);
    unsigned* hist = (unsigned*)(ws + 1200000);
    int* meta = (int*)(ws + 1216384);
    u64* keys = (u64*)(ws + 1216416);
    int* keptpos = (int*)(ws + 1281952);
    u64* masks = (u64*)(ws + 1286144);

    k_init<<<dim3(16), dim3(256), 0, stream>>>(hist, meta);
    k_scores<<<dim3((NBOX + 255) / 256), dim3(256), 0, stream>>>(in, scores, hist);
    k_thresh<<<dim3(1), dim3(1024), 0, stream>>>(hist, meta);
    k_compact<<<dim3((NBOX + 255) / 256), dim3(256), 0, stream>>>(scores, meta, keys);
    k_sort<<<dim3(1), dim3(1024), 0, stream>>>(keys, meta);
    k_masks<<<dim3(W64, W64), dim3(256), 0, stream>>>(in, keys, meta, masks);
    k_sweep<<<dim3(1), dim3(64), 0, stream>>>(masks, meta, keptpos);
    k_output<<<dim3((MAXKEEP + 255) / 256), dim3(256), 0, stream>>>(in, keys, meta, keptpos, out);
}

// Round 3
// 355.156 us; speedup vs baseline: 5.1158x; 1.1488x over previous
//
#include <hip/hip_runtime.h>

#define NBOX 300000
#define NFEAT 85
#define NCLS 80
#define NBUCK 4096
#define CMAX 8192
#define W64 (CMAX / 64)   // 128 mask words per candidate row
#define MAXKEEP 1000
#define SLOTS 64

typedef unsigned long long u64;

__device__ __forceinline__ int bucket_of(float s) {
    int b = (int)((s - 0.3f) * (4096.0f / 0.7f));
    if (b < 0) b = 0;
    if (b > NBUCK - 1) b = NBUCK - 1;
    return b;
}

__device__ __forceinline__ bool sup_iou(float by1, float bx1, float by2, float bx2, float ba,
                                        float y1, float x1, float y2, float x2, float area) {
    float iy1 = fmaxf(by1, y1), ix1 = fmaxf(bx1, x1);
    float iy2 = fminf(by2, y2), ix2 = fminf(bx2, x2);
    float inter = fmaxf(iy2 - iy1, 0.0f) * fmaxf(ix2 - ix1, 0.0f);
    float uni = ba + area - inter;
    float iou = (uni > 0.0f) ? inter / uni : 0.0f;
    return iou > 0.5f;
}

// n-th (0-based) set bit position of m (per-lane); undefined if n >= popcount(m)
__device__ __forceinline__ int nth_set(u64 m, int n) {
    int pos = 0;
    int c = __popcll(m & 0xFFFFFFFFull);
    if (n >= c) { n -= c; pos = 32; m >>= 32; }
    unsigned x = (unsigned)m;
    c = __popc(x & 0xFFFFu);
    if (n >= c) { n -= c; pos += 16; x >>= 16; }
    c = __popc(x & 0xFFu);
    if (n >= c) { n -= c; pos += 8; x >>= 8; }
    c = __popc(x & 0xFu);
    if (n >= c) { n -= c; pos += 4; x >>= 4; }
    c = __popc(x & 0x3u);
    if (n >= c) { n -= c; pos += 2; x >>= 2; }
    c = x & 1u;
    if (n >= c) { pos += 1; }
    return pos;
}

__global__ void k_init(unsigned* __restrict__ hist, unsigned* __restrict__ cnt,
                       int* __restrict__ meta) {
    int i = blockIdx.x * blockDim.x + threadIdx.x;
    if (i < NBUCK) { hist[i] = 0u; cnt[i] = 0u; }
    if (i < 8) meta[i] = 0;
}

__global__ void k_scores(const float* __restrict__ in, float* __restrict__ scores,
                         unsigned* __restrict__ hist) {
    int i = blockIdx.x * blockDim.x + threadIdx.x;
    if (i >= NBOX) return;
    const float* row = in + (long long)i * NFEAT;
    float conf = row[4];
    float best = -1.0f;
    #pragma unroll
    for (int j = 0; j < NCLS; ++j) best = fmaxf(best, conf * row[5 + j]);
    scores[i] = best;
    if (best >= 0.3f) atomicAdd(&hist[bucket_of(best)], 1u);
}

// Suffix sums over buckets (descending order), bucket threshold bstar = smallest b
// with suffix(b) <= CMAX, per-bucket descending offsets off[b] = suffix(b+1),
// meta[0] = total = suffix(bstar)  (deterministic top-prefix candidate set).
__global__ void __launch_bounds__(1024) k_thresh(const unsigned* __restrict__ hist,
                                                 unsigned* __restrict__ off,
                                                 int* __restrict__ meta) {
    __shared__ unsigned chunk[1024];
    int t = threadIdx.x;
    unsigned h[4];
    unsigned s = 0;
    #pragma unroll
    for (int j = 0; j < 4; ++j) { h[j] = hist[t * 4 + j]; s += h[j]; }
    chunk[t] = s;
    __syncthreads();
    for (int o = 1; o < 1024; o <<= 1) {
        unsigned add = (t + o < 1024) ? chunk[t + o] : 0u;
        __syncthreads();
        chunk[t] += add;
        __syncthreads();
    }
    unsigned after = (t + 1 < 1024) ? chunk[t + 1] : 0u;
    unsigned suf[5];
    suf[4] = after;
    #pragma unroll
    for (int j = 3; j >= 0; --j) suf[j] = suf[j + 1] + h[j];
    #pragma unroll
    for (int j = 0; j < 4; ++j) {
        int b = t * 4 + j;
        off[b] = suf[j] - h[j];                       // = suffix(b+1)
        unsigned sufb = suf[j];                       // suffix(b)
        unsigned sufprev;                             // suffix(b-1)
        if (b == 0) sufprev = 0xFFFFFFFFu;
        else if (j > 0) sufprev = suf[j - 1];
        else sufprev = sufb + hist[b - 1];
        if (sufb <= (unsigned)CMAX && sufprev > (unsigned)CMAX) {
            meta[1] = b;
            meta[0] = (int)sufb;
        }
    }
}

__global__ void k_scatter(const float* __restrict__ scores, const int* __restrict__ meta,
                          const unsigned* __restrict__ off, unsigned* __restrict__ cnt,
                          u64* __restrict__ unsorted) {
    int i = blockIdx.x * blockDim.x + threadIdx.x;
    if (i >= NBOX) return;
    float s = scores[i];
    if (s < 0.3f) return;
    int b = bucket_of(s);
    if (b < meta[1]) return;
    unsigned slot = off[b] + atomicAdd(&cnt[b], 1u);
    if (slot < CMAX)
        unsorted[slot] = ((u64)__float_as_uint(s) << 32) |
                         (u64)(0xFFFFFFFFu - (unsigned)i);
}

// Exact rank within bucket -> fully sorted, deterministic (keys unique).
__global__ void k_rank(const u64* __restrict__ unsorted, const unsigned* __restrict__ off,
                       const unsigned* __restrict__ hist, const int* __restrict__ meta,
                       u64* __restrict__ sorted) {
    int i = blockIdx.x * blockDim.x + threadIdx.x;
    int total = meta[0];
    if (i >= total) return;
    u64 k = unsorted[i];
    float s = __uint_as_float((unsigned)(k >> 32));
    int b = bucket_of(s);
    unsigned base = off[b];
    unsigned n = hist[b];
    unsigned r = 0;
    for (unsigned u = 0; u < n; ++u) r += (unsorted[base + u] > k) ? 1u : 0u;
    sorted[base + r] = k;
}

// Pairwise suppression masks: masks[i][w] bit b = (j = w*64+b) > i && IoU(i,j) > 0.5.
// Only words tj >= ti are written; sub-diagonal words are garbage (provably unread-effective).
__global__ void __launch_bounds__(256) k_masks(const float* __restrict__ in,
        const u64* __restrict__ gkeys, const int* __restrict__ meta,
        u64* __restrict__ masks) {
    int ti = blockIdx.y, tj = blockIdx.x;
    if (tj < ti) return;
    int count = meta[0];
    if (count > CMAX) count = CMAX;
    __shared__ float4 rb[64];
    int t = threadIdx.x;
    if (t < 64) {
        int r = ti * 64 + t;
        float4 b = make_float4(0.f, 0.f, 0.f, 0.f);
        if (r < count) {
            u64 key = gkeys[r];
            int bi = (int)(0xFFFFFFFFu - (unsigned)(key & 0xFFFFFFFFull));
            const float* p = in + (long long)bi * NFEAT;
            b = make_float4(p[0], p[1], p[2], p[3]);  // y1,x1,y2,x2
        }
        rb[t] = b;
    }
    int lane = t & 63, wid = t >> 6;
    int cj = tj * 64 + lane;
    float cy1 = 0.f, cx1 = 0.f, cy2 = 0.f, cx2 = 0.f, carea = 0.f;
    bool cvalid = (cj < count);
    if (cvalid) {
        u64 key = gkeys[cj];
        int bi = (int)(0xFFFFFFFFu - (unsigned)(key & 0xFFFFFFFFull));
        const float* p = in + (long long)bi * NFEAT;
        cy1 = p[0]; cx1 = p[1]; cy2 = p[2]; cx2 = p[3];
        carea = (cy2 - cy1) * (cx2 - cx1);
    }
    __syncthreads();
    #pragma unroll
    for (int r = 0; r < 16; ++r) {
        int i = ti * 64 + wid * 16 + r;
        float4 b = rb[wid * 16 + r];
        float ba = (b.z - b.x) * (b.w - b.y);
        bool s = cvalid && (cj > i) && (i < count) &&
                 sup_iou(b.x, b.y, b.z, b.w, ba, cy1, cx1, cy2, cx2, carea);
        u64 word = __ballot(s ? 1 : 0);
        if (lane == 0) masks[(size_t)i * W64 + tj] = word;
    }
}

// Block-pipelined greedy sweep. One wave. Lane l owns R words 2l, 2l+1.
// Per 64-block: survivors (from a speculative uniform removed-word) get their
// rows staged to LDS one block ahead (global_load_lds) + a gathered diagonal
// word; in-block greedy is a pure register/shfl chain; R-update ORs kept rows.
__global__ void __launch_bounds__(64) k_sweep(const u64* __restrict__ masks,
        int* __restrict__ meta, int* __restrict__ keptpos) {
    __shared__ __align__(16) u64 stage[2][SLOTS][W64];  // 128 KB
    int lane = threadIdx.x;
    int count = meta[0];
    if (count > CMAX) count = CMAX;
    int nblk = (count + 63) >> 6;
    u64 r0 = 0ull, r1 = 0ull;
    u64 surv_next = 0ull, colw_next = 0ull;
    int nk = 0;

    auto word_of = [&](int w) -> u64 {
        u64 v = (w & 1) ? r1 : r0;
        return __shfl(v, w >> 1);
    };

    auto prefetch = [&](int w, int pbuf) {
        u64 rem = word_of(w);  // speculative (R may lag one block): superset-safe
        int rc = count - (w << 6);
        u64 vm = (rc >= 64) ? ~0ull : ((rc <= 0) ? 0ull : ((1ull << rc) - 1ull));
        u64 surv = ~rem & vm;
        int ns = __popcll(surv);
        // gather: lane s < ns loads diagonal word w of survivor s's row
        int bs = nth_set(surv, lane < ns ? lane : 0);
        u64 cw = masks[(size_t)((w << 6) + bs) * W64 + w];
        // stage survivor rows (1 KB each) into LDS, one global_load_lds each
        u64 m = surv;
        int s = 0;
        while (m) {
            int bb = __ffsll(m) - 1;
            m &= m - 1;
            const unsigned int* gsrc =
                (const unsigned int*)&masks[(size_t)((w << 6) + bb) * W64] + lane * 4;
            __builtin_amdgcn_global_load_lds(
                (const __attribute__((address_space(1))) void*)gsrc,
                (__attribute__((address_space(3))) void*)&stage[pbuf][s][0],
                16, 0, 0);
            ++s;
        }
        surv_next = surv;
        colw_next = cw;
    };

    if (nblk > 0) prefetch(0, 0);
    int buf = 0;
    for (int w = 0; w < nblk && nk < MAXKEEP; ++w) {
        asm volatile("s_waitcnt vmcnt(0)" ::: "memory");
        u64 surv_cur = surv_next;
        u64 colw_cur = colw_next;
        int cbuf = buf;
        if (w + 1 < nblk) { buf ^= 1; prefetch(w + 1, buf); }

        // in-block serial greedy (register/shfl chain only)
        u64 rem = word_of(w);  // true removed word: R complete through block w-1
        int base = w << 6;
        u64 m = surv_cur & ~rem;
        u64 keptb = 0ull;
        while (m) {
            int b = __ffsll(m) - 1;
            m &= m - 1;
            if ((rem >> b) & 1ull) continue;
            int slot = __popcll(surv_cur & ((1ull << b) - 1ull));
            u64 cwb = __shfl(colw_cur, slot);
            rem |= cwb;
            keptb |= 1ull << b;
            if (lane == 0) keptpos[nk] = base + b;
            ++nk;
            if (nk >= MAXKEEP) break;
        }

        // R-update: OR kept rows from LDS, 4 rows in flight
        u64 km = keptb;
        while (km) {
            int b0 = __ffsll(km) - 1; km &= km - 1;
            int s0 = __popcll(surv_cur & ((1ull << b0) - 1ull));
            u64 lo0, hi0, lo1 = 0, hi1 = 0, lo2 = 0, hi2 = 0, lo3 = 0, hi3 = 0;
            { const u64* p = &stage[cbuf][s0][2 * lane]; lo0 = p[0]; hi0 = p[1]; }
            if (km) {
                int b = __ffsll(km) - 1; km &= km - 1;
                int sl = __popcll(surv_cur & ((1ull << b) - 1ull));
                const u64* p = &stage[cbuf][sl][2 * lane]; lo1 = p[0]; hi1 = p[1];
            }
            if (km) {
                int b = __ffsll(km) - 1; km &= km - 1;
                int sl = __popcll(surv_cur & ((1ull << b) - 1ull));
                const u64* p = &stage[cbuf][sl][2 * lane]; lo2 = p[0]; hi2 = p[1];
            }
            if (km) {
                int b = __ffsll(km) - 1; km &= km - 1;
                int sl = __popcll(surv_cur & ((1ull << b) - 1ull));
                const u64* p = &stage[cbuf][sl][2 * lane]; lo3 = p[0]; hi3 = p[1];
            }
            r0 |= lo0 | lo1 | lo2 | lo3;
            r1 |= hi0 | hi1 | hi2 | hi3;
        }
    }
    if (lane == 0) meta[2] = nk;
}

__global__ void k_output(const float* __restrict__ in, const u64* __restrict__ gkeys,
                         const int* __restrict__ meta, const int* __restrict__ keptpos,
                         float* __restrict__ out) {
    int r = blockIdx.x * blockDim.x + threadIdx.x;
    if (r >= MAXKEEP) return;
    int kc = meta[2];
    float o0 = 0.f, o1 = 0.f, o2 = 0.f, o3 = 0.f, o4 = 0.f, o5 = 0.f;
    if (r < kc) {
        int pos = keptpos[r];
        u64 key = gkeys[pos];
        int bi = (int)(0xFFFFFFFFu - (unsigned)(key & 0xFFFFFFFFull));
        const float* row = in + (long long)bi * NFEAT;
        o0 = row[0]; o1 = row[1]; o2 = row[2]; o3 = row[3];
        float conf = row[4];
        float best = -1.0f;
        int cls = 0;
        for (int j = 0; j < NCLS; ++j) {
            float s = conf * row[5 + j];
            if (s > best) { best = s; cls = j; }  // strict > : first occurrence, matches jnp.argmax
        }
        o4 = (float)cls; o5 = best;
    }
    float* orow = out + r * 6;
    orow[0] = o0; orow[1] = o1; orow[2] = o2;
    orow[3] = o3; orow[4] = o4; orow[5] = o5;
}

extern "C" void kernel_launch(void* const* d_in, const int* in_sizes, int n_in,
                              void* d_out, int out_size, void* d_ws, size_t ws_size,
                              hipStream_t stream) {
    const float* in = (const float*)d_in[0];
    float* out = (float*)d_out;
    char* ws = (char*)d_ws;
    // ws layout (bytes). masks OVERLAYS the sort-phase scratch (scores/hist/cnt/
    // off/unsorted are all dead before k_masks writes). Persistent-after-masks
    // buffers (sorted, meta, keptpos) live outside the masks region.
    //   [0, 65536)              sorted   u64[8192]
    //   [65536, 65600)          meta     i32[8]  {0:total, 1:bstar, 2:kept count}
    //   [65600, 69696)          keptpos  i32[1024]
    //   [69888, 8458496)        masks    u64[8192*128]  (8 MB), overlaying:
    //     [69888, 1269888)        scores   f32[300000]
    //     [1269888, 1286272)      hist     u32[4096]
    //     [1286272, 1302656)      cnt      u32[4096]
    //     [1302656, 1319040)      off      u32[4096]
    //     [1319040, 1384576)      unsorted u64[8192]
    u64* sorted = (u64*)(ws);
    int* meta = (int*)(ws + 65536);
    int* keptpos = (int*)(ws + 65600);
    u64* masks = (u64*)(ws + 69888);
    float* scores = (float*)(ws + 69888);
    unsigned* hist = (unsigned*)(ws + 1269888);
    unsigned* cnt = (unsigned*)(ws + 1286272);
    unsigned* off = (unsigned*)(ws + 1302656);
    u64* unsorted = (u64*)(ws + 1319040);

    k_init<<<dim3(16), dim3(256), 0, stream>>>(hist, cnt, meta);
    k_scores<<<dim3((NBOX + 255) / 256), dim3(256), 0, stream>>>(in, scores, hist);
    k_thresh<<<dim3(1), dim3(1024), 0, stream>>>(hist, off, meta);
    k_scatter<<<dim3((NBOX + 255) / 256), dim3(256), 0, stream>>>(scores, meta, off, cnt, unsorted);
    k_rank<<<dim3(CMAX / 256), dim3(256), 0, stream>>>(unsorted, off, hist, meta, sorted);
    k_masks<<<dim3(W64, W64), dim3(256), 0, stream>>>(in, sorted, meta, masks);
    k_sweep<<<dim3(1), dim3(64), 0, stream>>>(masks, meta, keptpos);
    k_output<<<dim3((MAXKEEP + 255) / 256), dim3(256), 0, stream>>>(in, sorted, meta, keptpos, out);
}

// Round 4
// 174.856 us; speedup vs baseline: 10.3909x; 2.0311x over previous
//
#include <hip/hip_runtime.h>

#define NBOX 300000
#define NFEAT 85
#define NCLS 80
#define NBUCK 4096
#define CMAX 8192
#define W64 (CMAX / 64)   // 128 mask words per candidate row
#define MAXKEEP 1000

typedef unsigned long long u64;

__device__ __forceinline__ int bucket_of(float s) {
    int b = (int)((s - 0.3f) * (4096.0f / 0.7f));
    if (b < 0) b = 0;
    if (b > NBUCK - 1) b = NBUCK - 1;
    return b;
}

__device__ __forceinline__ bool sup_iou(float by1, float bx1, float by2, float bx2, float ba,
                                        float y1, float x1, float y2, float x2, float area) {
    float iy1 = fmaxf(by1, y1), ix1 = fmaxf(bx1, x1);
    float iy2 = fminf(by2, y2), ix2 = fminf(bx2, x2);
    float inter = fmaxf(iy2 - iy1, 0.0f) * fmaxf(ix2 - ix1, 0.0f);
    float uni = ba + area - inter;
    float iou = (uni > 0.0f) ? inter / uni : 0.0f;
    return iou > 0.5f;
}

// n-th (0-based) set bit position of m; undefined if n >= popcount(m)
__device__ __forceinline__ int nth_set(u64 m, int n) {
    int pos = 0;
    int c = __popcll(m & 0xFFFFFFFFull);
    if (n >= c) { n -= c; pos = 32; m >>= 32; }
    unsigned x = (unsigned)m;
    c = __popc(x & 0xFFFFu);
    if (n >= c) { n -= c; pos += 16; x >>= 16; }
    c = __popc(x & 0xFFu);
    if (n >= c) { n -= c; pos += 8; x >>= 8; }
    c = __popc(x & 0xFu);
    if (n >= c) { n -= c; pos += 4; x >>= 4; }
    c = __popc(x & 0x3u);
    if (n >= c) { n -= c; pos += 2; x >>= 2; }
    c = x & 1u;
    if (n >= c) { pos += 1; }
    return pos;
}

__global__ void k_init(unsigned* __restrict__ hist, unsigned* __restrict__ cnt,
                       int* __restrict__ meta) {
    int i = blockIdx.x * blockDim.x + threadIdx.x;
    if (i < NBUCK) { hist[i] = 0u; cnt[i] = 0u; }
    if (i < 8) meta[i] = 0;
}

// 1 wave per 64 rows: coalesced float4 -> LDS stage, then per-lane row max.
__global__ void __launch_bounds__(64) k_scores(const float* __restrict__ in,
        float* __restrict__ scores, unsigned* __restrict__ hist) {
    __shared__ float lds[64 * NFEAT];  // 21760 B
    int lane = threadIdx.x;
    long long base = (long long)blockIdx.x * 64;
    int rows = (NBOX - base < 64) ? (int)(NBOX - base) : 64;
    int nfl = rows * NFEAT;
    int nf4 = nfl >> 2;
    const float4* src = (const float4*)(in + base * NFEAT);  // 16B-aligned (64*85*4 % 16 == 0)
    float4* dst = (float4*)lds;
    for (int k = lane; k < nf4; k += 64) dst[k] = src[k];
    for (int k = (nf4 << 2) + lane; k < nfl; k += 64) lds[k] = in[base * NFEAT + k];
    __syncthreads();
    if (lane < rows) {
        const float* row = lds + lane * NFEAT;
        float conf = row[4];
        float best = -1.0f;
        #pragma unroll
        for (int j = 0; j < NCLS; ++j) best = fmaxf(best, conf * row[5 + j]);
        scores[base + lane] = best;
        if (best >= 0.3f) atomicAdd(&hist[bucket_of(best)], 1u);
    }
}

// Suffix sums over buckets; bstar = smallest b with suffix(b) <= CMAX;
// off[b] = suffix(b+1); meta[0] = suffix(bstar) (deterministic top-prefix).
__global__ void __launch_bounds__(1024) k_thresh(const unsigned* __restrict__ hist,
                                                 unsigned* __restrict__ off,
                                                 int* __restrict__ meta) {
    __shared__ unsigned chunk[1024];
    int t = threadIdx.x;
    unsigned h[4];
    unsigned s = 0;
    #pragma unroll
    for (int j = 0; j < 4; ++j) { h[j] = hist[t * 4 + j]; s += h[j]; }
    chunk[t] = s;
    __syncthreads();
    for (int o = 1; o < 1024; o <<= 1) {
        unsigned add = (t + o < 1024) ? chunk[t + o] : 0u;
        __syncthreads();
        chunk[t] += add;
        __syncthreads();
    }
    unsigned after = (t + 1 < 1024) ? chunk[t + 1] : 0u;
    unsigned suf[5];
    suf[4] = after;
    #pragma unroll
    for (int j = 3; j >= 0; --j) suf[j] = suf[j + 1] + h[j];
    #pragma unroll
    for (int j = 0; j < 4; ++j) {
        int b = t * 4 + j;
        off[b] = suf[j] - h[j];
        unsigned sufb = suf[j];
        unsigned sufprev;
        if (b == 0) sufprev = 0xFFFFFFFFu;
        else if (j > 0) sufprev = suf[j - 1];
        else sufprev = sufb + hist[b - 1];
        if (sufb <= (unsigned)CMAX && sufprev > (unsigned)CMAX) {
            meta[1] = b;
            meta[0] = (int)sufb;
        }
    }
}

__global__ void k_scatter(const float* __restrict__ scores, const int* __restrict__ meta,
                          const unsigned* __restrict__ off, unsigned* __restrict__ cnt,
                          u64* __restrict__ unsorted) {
    int i = blockIdx.x * blockDim.x + threadIdx.x;
    if (i >= NBOX) return;
    float s = scores[i];
    if (s < 0.3f) return;
    int b = bucket_of(s);
    if (b < meta[1]) return;
    unsigned slot = off[b] + atomicAdd(&cnt[b], 1u);
    if (slot < CMAX)
        unsorted[slot] = ((u64)__float_as_uint(s) << 32) |
                         (u64)(0xFFFFFFFFu - (unsigned)i);
}

// Exact rank within bucket -> fully sorted, deterministic (keys unique).
__global__ void k_rank(const u64* __restrict__ unsorted, const unsigned* __restrict__ off,
                       const unsigned* __restrict__ hist, const int* __restrict__ meta,
                       u64* __restrict__ sorted) {
    int i = blockIdx.x * blockDim.x + threadIdx.x;
    int total = meta[0];
    if (i >= total) return;
    u64 k = unsorted[i];
    float s = __uint_as_float((unsigned)(k >> 32));
    int b = bucket_of(s);
    unsigned base = off[b];
    unsigned n = hist[b];
    unsigned r = 0;
    for (unsigned u = 0; u < n; ++u) r += (unsorted[base + u] > k) ? 1u : 0u;
    sorted[base + r] = k;
}

// masks[i][w] bit b = (j = w*64+b) > i && IoU(i,j) > 0.5.  Words tj >= ti written;
// sub-diagonal words are garbage (only ever OR'd into already-consumed R words).
__global__ void __launch_bounds__(256) k_masks(const float* __restrict__ in,
        const u64* __restrict__ gkeys, const int* __restrict__ meta,
        u64* __restrict__ masks) {
    int ti = blockIdx.y, tj = blockIdx.x;
    if (tj < ti) return;
    int count = meta[0];
    if (count > CMAX) count = CMAX;
    __shared__ float4 rb[64];
    int t = threadIdx.x;
    if (t < 64) {
        int r = ti * 64 + t;
        float4 b = make_float4(0.f, 0.f, 0.f, 0.f);
        if (r < count) {
            u64 key = gkeys[r];
            int bi = (int)(0xFFFFFFFFu - (unsigned)(key & 0xFFFFFFFFull));
            const float* p = in + (long long)bi * NFEAT;
            b = make_float4(p[0], p[1], p[2], p[3]);
        }
        rb[t] = b;
    }
    int lane = t & 63, wid = t >> 6;
    int cj = tj * 64 + lane;
    float cy1 = 0.f, cx1 = 0.f, cy2 = 0.f, cx2 = 0.f, carea = 0.f;
    bool cvalid = (cj < count);
    if (cvalid) {
        u64 key = gkeys[cj];
        int bi = (int)(0xFFFFFFFFu - (unsigned)(key & 0xFFFFFFFFull));
        const float* p = in + (long long)bi * NFEAT;
        cy1 = p[0]; cx1 = p[1]; cy2 = p[2]; cx2 = p[3];
        carea = (cy2 - cy1) * (cx2 - cx1);
    }
    __syncthreads();
    #pragma unroll
    for (int r = 0; r < 16; ++r) {
        int i = ti * 64 + wid * 16 + r;
        float4 b = rb[wid * 16 + r];
        float ba = (b.z - b.x) * (b.w - b.y);
        bool s = cvalid && (cj > i) && (i < count) &&
                 sup_iou(b.x, b.y, b.z, b.w, ba, cy1, cx1, cy2, cx2, carea);
        u64 word = __ballot(s ? 1 : 0);
        if (lane == 0) masks[(size_t)i * W64 + tj] = word;
    }
}

// Greedy sweep, one wave. Lane l owns R words 2l, 2l+1.
// Per block w: per-candidate diag word (gathered one block ahead, R-independent),
// Z = ballot(diag==0) skips no-op candidates in the serial chain, kept rows
// loaded as 32-wide static-register batches (coalesced dwordx4 per row).
__global__ void __launch_bounds__(64) k_sweep(const u64* __restrict__ masks,
        int* __restrict__ meta, int* __restrict__ keptpos) {
    int lane = threadIdx.x;
    int count = meta[0];
    if (count > CMAX) count = CMAX;
    int nblk = (count + 63) >> 6;
    u64 r0 = 0ull, r1 = 0ull;
    int nk = 0;

    // diag for block 0: lane j holds masks[j][0]
    u64 diag_cur = (nblk > 0) ? masks[(size_t)lane * W64] : 0ull;

    for (int w = 0; w < nblk && nk < MAXKEEP; ++w) {
        int base = w << 6;
        int rc = count - base;
        u64 vm = (rc >= 64) ? ~0ull : ((1ull << rc) - 1ull);
        u64 rw = __shfl((w & 1) ? r1 : r0, w >> 1);
        u64 surv = ~rw & vm;

        // gather diag for w+1 (independent of R; latency hidden under this block)
        u64 diag_next = 0ull;
        if (w + 1 < nblk)
            diag_next = masks[(size_t)((w + 1) * 64 + lane) * W64 + (w + 1)];

        // in-block greedy: only nonzero-diag candidates enter the serial chain
        u64 Z = __ballot(diag_cur == 0ull);
        u64 rem_l = 0ull;
        u64 mnz = surv & ~Z;
        while (mnz) {
            int b = __ffsll(mnz) - 1;
            mnz &= mnz - 1;
            if ((rem_l >> b) & 1ull) continue;
            u64 db = __shfl(diag_cur, b);
            rem_l |= db;
            mnz &= ~db;
        }
        u64 kept = surv & ~rem_l;

        // truncate to exactly MAXKEEP in index order (suppression flows forward only)
        int kp = __popcll(kept);
        int room = MAXKEEP - nk;
        if (kp > room) {
            while (kp > room) { kept &= ~(1ull << (63 - __clzll(kept))); --kp; }
        }
        if (lane < kp) keptpos[nk + lane] = base + nth_set(kept, lane);
        nk += kp;
        if (nk >= MAXKEEP) break;

        // OR kept rows into R: 32 independent coalesced loads in flight per round
        u64 km = kept;
        while (km) {
            u64 lo[32], hi[32];
            u64 t = km;
            #pragma unroll
            for (int k = 0; k < 32; ++k) {
                bool has = (t != 0ull);
                int b = has ? (__ffsll(t) - 1) : 0;
                t &= t - 1;
                const u64* p = masks + (size_t)(base + b) * W64 + 2 * lane;
                lo[k] = has ? p[0] : 0ull;
                hi[k] = has ? p[1] : 0ull;
            }
            km = t;
            u64 alo = 0ull, ahi = 0ull;
            #pragma unroll
            for (int k = 0; k < 32; ++k) { alo |= lo[k]; ahi |= hi[k]; }
            r0 |= alo; r1 |= ahi;
        }

        diag_cur = diag_next;
    }
    if (lane == 0) meta[2] = nk;
}

__global__ void k_output(const float* __restrict__ in, const u64* __restrict__ gkeys,
                         const int* __restrict__ meta, const int* __restrict__ keptpos,
                         float* __restrict__ out) {
    int r = blockIdx.x * blockDim.x + threadIdx.x;
    if (r >= MAXKEEP) return;
    int kc = meta[2];
    float o0 = 0.f, o1 = 0.f, o2 = 0.f, o3 = 0.f, o4 = 0.f, o5 = 0.f;
    if (r < kc) {
        int pos = keptpos[r];
        u64 key = gkeys[pos];
        int bi = (int)(0xFFFFFFFFu - (unsigned)(key & 0xFFFFFFFFull));
        const float* row = in + (long long)bi * NFEAT;
        o0 = row[0]; o1 = row[1]; o2 = row[2]; o3 = row[3];
        float conf = row[4];
        float best = -1.0f;
        int cls = 0;
        for (int j = 0; j < NCLS; ++j) {
            float s = conf * row[5 + j];
            if (s > best) { best = s; cls = j; }  // strict > : first occurrence = jnp.argmax
        }
        o4 = (float)cls; o5 = best;
    }
    float* orow = out + r * 6;
    orow[0] = o0; orow[1] = o1; orow[2] = o2;
    orow[3] = o3; orow[4] = o4; orow[5] = o5;
}

extern "C" void kernel_launch(void* const* d_in, const int* in_sizes, int n_in,
                              void* d_out, int out_size, void* d_ws, size_t ws_size,
                              hipStream_t stream) {
    const float* in = (const float*)d_in[0];
    float* out = (float*)d_out;
    char* ws = (char*)d_ws;
    // ws layout (bytes). masks OVERLAYS sort-phase scratch (dead before k_masks).
    //   [0, 65536)              sorted   u64[8192]
    //   [65536, 65600)          meta     i32[8]  {0:total, 1:bstar, 2:kept count}
    //   [65600, 69696)          keptpos  i32[1024]
    //   [69888, 8458496)        masks    u64[8192*128]  (8 MB), overlaying:
    //     [69888, 1269888)        scores   f32[300000]
    //     [1269888, 1286272)      hist     u32[4096]
    //     [1286272, 1302656)      cnt      u32[4096]
    //     [1302656, 1319040)      off      u32[4096]
    //     [1319040, 1384576)      unsorted u64[8192]
    u64* sorted = (u64*)(ws);
    int* meta = (int*)(ws + 65536);
    int* keptpos = (int*)(ws + 65600);
    u64* masks = (u64*)(ws + 69888);
    float* scores = (float*)(ws + 69888);
    unsigned* hist = (unsigned*)(ws + 1269888);
    unsigned* cnt = (unsigned*)(ws + 1286272);
    unsigned* off = (unsigned*)(ws + 1302656);
    u64* unsorted = (u64*)(ws + 1319040);

    k_init<<<dim3(16), dim3(256), 0, stream>>>(hist, cnt, meta);
    k_scores<<<dim3((NBOX + 63) / 64), dim3(64), 0, stream>>>(in, scores, hist);
    k_thresh<<<dim3(1), dim3(1024), 0, stream>>>(hist, off, meta);
    k_scatter<<<dim3((NBOX + 255) / 256), dim3(256), 0, stream>>>(scores, meta, off, cnt, unsorted);
    k_rank<<<dim3(CMAX / 256), dim3(256), 0, stream>>>(unsorted, off, hist, meta, sorted);
    k_masks<<<dim3(W64, W64), dim3(256), 0, stream>>>(in, sorted, meta, masks);
    k_sweep<<<dim3(1), dim3(64), 0, stream>>>(masks, meta, keptpos);
    k_output<<<dim3((MAXKEEP + 255) / 256), dim3(256), 0, stream>>>(in, sorted, meta, keptpos, out);
}

// Round 5
// 153.795 us; speedup vs baseline: 11.8138x; 1.1369x over previous
//
#include <hip/hip_runtime.h>

#define NBOX 300000
#define NFEAT 85
#define NCLS 80
#define NBUCK 4096
#define CMAX 8192
#define W64 (CMAX / 64)   // 128 mask words per candidate row
#define MAXKEEP 1000
#define PRE 24            // prefetched rows per block (exact-spec, cap)

typedef unsigned long long u64;

__device__ __forceinline__ int bucket_of(float s) {
    int b = (int)((s - 0.3f) * (4096.0f / 0.7f));
    if (b < 0) b = 0;
    if (b > NBUCK - 1) b = NBUCK - 1;
    return b;
}

__device__ __forceinline__ bool sup_iou(float by1, float bx1, float by2, float bx2, float ba,
                                        float y1, float x1, float y2, float x2, float area) {
    float iy1 = fmaxf(by1, y1), ix1 = fmaxf(bx1, x1);
    float iy2 = fminf(by2, y2), ix2 = fminf(bx2, x2);
    float inter = fmaxf(iy2 - iy1, 0.0f) * fmaxf(ix2 - ix1, 0.0f);
    float uni = ba + area - inter;
    float iou = (uni > 0.0f) ? inter / uni : 0.0f;
    return iou > 0.5f;
}

// n-th (0-based) set bit position of m; undefined if n >= popcount(m)
__device__ __forceinline__ int nth_set(u64 m, int n) {
    int pos = 0;
    int c = __popcll(m & 0xFFFFFFFFull);
    if (n >= c) { n -= c; pos = 32; m >>= 32; }
    unsigned x = (unsigned)m;
    c = __popc(x & 0xFFFFu);
    if (n >= c) { n -= c; pos += 16; x >>= 16; }
    c = __popc(x & 0xFFu);
    if (n >= c) { n -= c; pos += 8; x >>= 8; }
    c = __popc(x & 0xFu);
    if (n >= c) { n -= c; pos += 4; x >>= 4; }
    c = __popc(x & 0x3u);
    if (n >= c) { n -= c; pos += 2; x >>= 2; }
    c = x & 1u;
    if (n >= c) { pos += 1; }
    return pos;
}

__global__ void k_init(unsigned* __restrict__ hist, unsigned* __restrict__ cnt,
                       int* __restrict__ meta) {
    int i = blockIdx.x * blockDim.x + threadIdx.x;
    if (i < NBUCK) { hist[i] = 0u; cnt[i] = 0u; }
    if (i < 8) meta[i] = 0;
}

// 1 wave per 64 rows: coalesced float4 -> LDS stage, then per-lane row max.
__global__ void __launch_bounds__(64) k_scores(const float* __restrict__ in,
        float* __restrict__ scores, unsigned* __restrict__ hist) {
    __shared__ float lds[64 * NFEAT];  // 21760 B
    int lane = threadIdx.x;
    long long base = (long long)blockIdx.x * 64;
    int rows = (NBOX - base < 64) ? (int)(NBOX - base) : 64;
    int nfl = rows * NFEAT;
    int nf4 = nfl >> 2;
    const float4* src = (const float4*)(in + base * NFEAT);  // 16B-aligned
    float4* dst = (float4*)lds;
    for (int k = lane; k < nf4; k += 64) dst[k] = src[k];
    for (int k = (nf4 << 2) + lane; k < nfl; k += 64) lds[k] = in[base * NFEAT + k];
    __syncthreads();
    if (lane < rows) {
        const float* row = lds + lane * NFEAT;
        float conf = row[4];
        float best = -1.0f;
        #pragma unroll
        for (int j = 0; j < NCLS; ++j) best = fmaxf(best, conf * row[5 + j]);
        scores[base + lane] = best;
        if (best >= 0.3f) atomicAdd(&hist[bucket_of(best)], 1u);
    }
}

// Suffix sums over buckets; bstar = smallest b with suffix(b) <= CMAX;
// off[b] = suffix(b+1); meta[0] = suffix(bstar) (deterministic top-prefix).
__global__ void __launch_bounds__(1024) k_thresh(const unsigned* __restrict__ hist,
                                                 unsigned* __restrict__ off,
                                                 int* __restrict__ meta) {
    __shared__ unsigned chunk[1024];
    int t = threadIdx.x;
    unsigned h[4];
    unsigned s = 0;
    #pragma unroll
    for (int j = 0; j < 4; ++j) { h[j] = hist[t * 4 + j]; s += h[j]; }
    chunk[t] = s;
    __syncthreads();
    for (int o = 1; o < 1024; o <<= 1) {
        unsigned add = (t + o < 1024) ? chunk[t + o] : 0u;
        __syncthreads();
        chunk[t] += add;
        __syncthreads();
    }
    unsigned after = (t + 1 < 1024) ? chunk[t + 1] : 0u;
    unsigned suf[5];
    suf[4] = after;
    #pragma unroll
    for (int j = 3; j >= 0; --j) suf[j] = suf[j + 1] + h[j];
    #pragma unroll
    for (int j = 0; j < 4; ++j) {
        int b = t * 4 + j;
        off[b] = suf[j] - h[j];
        unsigned sufb = suf[j];
        unsigned sufprev;
        if (b == 0) sufprev = 0xFFFFFFFFu;
        else if (j > 0) sufprev = suf[j - 1];
        else sufprev = sufb + hist[b - 1];
        if (sufb <= (unsigned)CMAX && sufprev > (unsigned)CMAX) {
            meta[1] = b;
            meta[0] = (int)sufb;
        }
    }
}

__global__ void k_scatter(const float* __restrict__ scores, const int* __restrict__ meta,
                          const unsigned* __restrict__ off, unsigned* __restrict__ cnt,
                          u64* __restrict__ unsorted) {
    int i = blockIdx.x * blockDim.x + threadIdx.x;
    if (i >= NBOX) return;
    float s = scores[i];
    if (s < 0.3f) return;
    int b = bucket_of(s);
    if (b < meta[1]) return;
    unsigned slot = off[b] + atomicAdd(&cnt[b], 1u);
    if (slot < CMAX)
        unsorted[slot] = ((u64)__float_as_uint(s) << 32) |
                         (u64)(0xFFFFFFFFu - (unsigned)i);
}

// Exact rank within bucket -> fully sorted, deterministic (keys unique).
__global__ void k_rank(const u64* __restrict__ unsorted, const unsigned* __restrict__ off,
                       const unsigned* __restrict__ hist, const int* __restrict__ meta,
                       u64* __restrict__ sorted) {
    int i = blockIdx.x * blockDim.x + threadIdx.x;
    int total = meta[0];
    if (i >= total) return;
    u64 k = unsorted[i];
    float s = __uint_as_float((unsigned)(k >> 32));
    int b = bucket_of(s);
    unsigned base = off[b];
    unsigned n = hist[b];
    unsigned r = 0;
    for (unsigned u = 0; u < n; ++u) r += (unsorted[base + u] > k) ? 1u : 0u;
    sorted[base + r] = k;
}

// masks[i][w] bit b = (j = w*64+b) > i && IoU(i,j) > 0.5.  Words tj >= ti written
// (0 for invalid i/j). Diag blocks also emit validmask[ti] (bit r = row has
// positive extents; zero-extent rows provably have all-zero mask rows).
__global__ void __launch_bounds__(256) k_masks(const float* __restrict__ in,
        const u64* __restrict__ gkeys, const int* __restrict__ meta,
        u64* __restrict__ masks, u64* __restrict__ validmask) {
    int ti = blockIdx.y, tj = blockIdx.x;
    if (tj < ti) return;
    int count = meta[0];
    if (count > CMAX) count = CMAX;
    __shared__ float4 rb[64];
    int t = threadIdx.x;
    if (t < 64) {
        int r = ti * 64 + t;
        float4 b = make_float4(0.f, 0.f, 0.f, 0.f);
        if (r < count) {
            u64 key = gkeys[r];
            int bi = (int)(0xFFFFFFFFu - (unsigned)(key & 0xFFFFFFFFull));
            const float* p = in + (long long)bi * NFEAT;
            b = make_float4(p[0], p[1], p[2], p[3]);  // y1,x1,y2,x2
        }
        rb[t] = b;
    }
    int lane = t & 63, wid = t >> 6;
    int cj = tj * 64 + lane;
    float cy1 = 0.f, cx1 = 0.f, cy2 = 0.f, cx2 = 0.f, carea = 0.f;
    bool cvalid = (cj < count);
    if (cvalid) {
        u64 key = gkeys[cj];
        int bi = (int)(0xFFFFFFFFu - (unsigned)(key & 0xFFFFFFFFull));
        const float* p = in + (long long)bi * NFEAT;
        cy1 = p[0]; cx1 = p[1]; cy2 = p[2]; cx2 = p[3];
        carea = (cy2 - cy1) * (cx2 - cx1);
    }
    __syncthreads();
    if (ti == tj && t < 64) {   // wave 0 exactly: ballot is wave-wide
        float4 b = rb[t];
        bool v = (b.z > b.x) && (b.w > b.y);
        u64 vb = __ballot(v ? 1 : 0);
        if (t == 0) validmask[ti] = vb;
    }
    #pragma unroll
    for (int r = 0; r < 16; ++r) {
        int i = ti * 64 + wid * 16 + r;
        float4 b = rb[wid * 16 + r];
        float ba = (b.z - b.x) * (b.w - b.y);
        bool s = cvalid && (cj > i) && (i < count) &&
                 sup_iou(b.x, b.y, b.z, b.w, ba, cy1, cx1, cy2, cx2, carea);
        u64 word = __ballot(s ? 1 : 0);
        if (lane == 0) masks[(size_t)i * W64 + tj] = word;
    }
}

// Greedy sweep, one wave. Lane l owns R/valid words 2l, 2l+1.
// Per block w: diag word gathered one block ahead; greedy chain gated by
// Z=ballot(diag==0); row-OR uses EXACT next-block prefetch (spec = ~R & valid
// computed after R is final through w, <=PRE rows into static registers);
// degenerate (invalid) rows are provably all-zero and never loaded.
__global__ void __launch_bounds__(64) k_sweep(const u64* __restrict__ masks,
        const u64* __restrict__ validmask, int* __restrict__ meta,
        int* __restrict__ keptpos) {
    int lane = threadIdx.x;
    int count = meta[0];
    if (count > CMAX) count = CMAX;
    int nblk = (count + 63) >> 6;
    u64 r0 = 0ull, r1 = 0ull;
    u64 v0 = validmask[2 * lane], v1 = validmask[2 * lane + 1];
    int nk = 0;

    u64 pre_lo[PRE], pre_hi[PRE];
    u64 spec_cur = 0ull, diag_cur = 0ull;

    if (nblk > 0) {
        diag_cur = masks[(size_t)lane * W64];  // diag word of block 0
        int rc = count;
        u64 vm0 = (rc >= 64) ? ~0ull : ((1ull << rc) - 1ull);
        spec_cur = __shfl(v0, 0) & vm0;        // valid & surv(0)=vm
        u64 t = spec_cur;
        #pragma unroll
        for (int k = 0; k < PRE; ++k) {
            bool has = (t != 0ull);
            int b = has ? (__ffsll(t) - 1) : 0;
            t &= t - 1;
            const u64* p = masks + (size_t)b * W64 + 2 * lane;
            pre_lo[k] = p[0]; pre_hi[k] = p[1];  // dup row-0 loads when !has (L2-hit)
        }
    }

    for (int w = 0; w < nblk && nk < MAXKEEP; ++w) {
        int base = w << 6;
        int rc = count - base;
        u64 vm = (rc >= 64) ? ~0ull : ((1ull << rc) - 1ull);
        u64 rw = __shfl((w & 1) ? r1 : r0, w >> 1);
        u64 surv = ~rw & vm;

        // diag gather for w+1: issued now, consumed next iteration (fully hidden)
        u64 diag_next = 0ull;
        if (w + 1 < nblk)
            diag_next = masks[(size_t)((w + 1) * 64 + lane) * W64 + (w + 1)];

        // in-block greedy: only nonzero-diag candidates enter the serial chain
        u64 Z = __ballot(diag_cur == 0ull);
        u64 rem_l = 0ull;
        u64 mnz = surv & ~Z;
        while (mnz) {
            int b = __ffsll(mnz) - 1;
            mnz &= mnz - 1;
            if ((rem_l >> b) & 1ull) continue;
            u64 db = __shfl(diag_cur, b);
            rem_l |= db;
            mnz &= ~db;
        }
        u64 kept = surv & ~rem_l;

        // truncate to exactly MAXKEEP in index order
        int kp = __popcll(kept);
        int room = MAXKEEP - nk;
        if (kp > room) {
            while (kp > room) { kept &= ~(1ull << (63 - __clzll(kept))); --kp; }
        }
        if (lane < kp) keptpos[nk + lane] = base + nth_set(kept, lane);
        nk += kp;
        if (nk >= MAXKEEP) break;

        // OR kept&valid rows from prefetched regs (walk mirrors the issue walk)
        {
            u64 t = spec_cur;
            u64 alo = 0ull, ahi = 0ull;
            #pragma unroll
            for (int k = 0; k < PRE; ++k) {
                bool has = (t != 0ull);
                int b = has ? (__ffsll(t) - 1) : 0;
                t &= t - 1;
                bool use = has && (((kept >> b) & 1ull) != 0ull);
                alo |= use ? pre_lo[k] : 0ull;
                ahi |= use ? pre_hi[k] : 0ull;
            }
            // fallback: kept rows beyond the PRE cap (t == spec remainder)
            u64 km = kept & t;
            while (km) {
                int b = __ffsll(km) - 1;
                km &= km - 1;
                const u64* p = masks + (size_t)(base + b) * W64 + 2 * lane;
                alo |= p[0]; ahi |= p[1];
            }
            r0 |= alo; r1 |= ahi;
        }

        // prefetch rows for w+1: R final through w -> spec is EXACT surv&valid
        if (w + 1 < nblk) {
            int base2 = base + 64;
            int rc2 = count - base2;
            u64 vm2 = (rc2 >= 64) ? ~0ull : ((rc2 <= 0) ? 0ull : ((1ull << rc2) - 1ull));
            int w2 = w + 1;
            u64 rw2 = __shfl((w2 & 1) ? r1 : r0, w2 >> 1);
            u64 vw2 = __shfl((w2 & 1) ? v1 : v0, w2 >> 1);
            spec_cur = ~rw2 & vw2 & vm2;
            u64 t = spec_cur;
            #pragma unroll
            for (int k = 0; k < PRE; ++k) {
                bool has = (t != 0ull);
                int b = has ? (__ffsll(t) - 1) : 0;
                t &= t - 1;
                const u64* p = masks + (size_t)(base2 + b) * W64 + 2 * lane;
                pre_lo[k] = p[0]; pre_hi[k] = p[1];
            }
        }
        diag_cur = diag_next;
    }
    if (lane == 0) meta[2] = nk;
}

__global__ void k_output(const float* __restrict__ in, const u64* __restrict__ gkeys,
                         const int* __restrict__ meta, const int* __restrict__ keptpos,
                         float* __restrict__ out) {
    int r = blockIdx.x * blockDim.x + threadIdx.x;
    if (r >= MAXKEEP) return;
    int kc = meta[2];
    float o0 = 0.f, o1 = 0.f, o2 = 0.f, o3 = 0.f, o4 = 0.f, o5 = 0.f;
    if (r < kc) {
        int pos = keptpos[r];
        u64 key = gkeys[pos];
        int bi = (int)(0xFFFFFFFFu - (unsigned)(key & 0xFFFFFFFFull));
        const float* row = in + (long long)bi * NFEAT;
        o0 = row[0]; o1 = row[1]; o2 = row[2]; o3 = row[3];
        float conf = row[4];
        float best = -1.0f;
        int cls = 0;
        for (int j = 0; j < NCLS; ++j) {
            float s = conf * row[5 + j];
            if (s > best) { best = s; cls = j; }  // strict > : first occurrence = jnp.argmax
        }
        o4 = (float)cls; o5 = best;
    }
    float* orow = out + r * 6;
    orow[0] = o0; orow[1] = o1; orow[2] = o2;
    orow[3] = o3; orow[4] = o4; orow[5] = o5;
}

extern "C" void kernel_launch(void* const* d_in, const int* in_sizes, int n_in,
                              void* d_out, int out_size, void* d_ws, size_t ws_size,
                              hipStream_t stream) {
    const float* in = (const float*)d_in[0];
    float* out = (float*)d_out;
    char* ws = (char*)d_ws;
    // ws layout (bytes). masks OVERLAYS sort-phase scratch (dead before k_masks).
    //   [0, 65536)              sorted    u64[8192]
    //   [65536, 65600)          meta      i32[8]  {0:total, 1:bstar, 2:kept count}
    //   [65600, 69696)          keptpos   i32[1024]
    //   [69696, 70720)          validmask u64[128]
    //   [70720, 8459328)        masks     u64[8192*128]  (8 MB), overlaying:
    //     [70720, 1270720)        scores   f32[300000]
    //     [1270720, 1287104)      hist     u32[4096]
    //     [1287104, 1303488)      cnt      u32[4096]
    //     [1303488, 1319872)      off      u32[4096]
    //     [1319872, 1385408)      unsorted u64[8192]
    u64* sorted = (u64*)(ws);
    int* meta = (int*)(ws + 65536);
    int* keptpos = (int*)(ws + 65600);
    u64* validmask = (u64*)(ws + 69696);
    u64* masks = (u64*)(ws + 70720);
    float* scores = (float*)(ws + 70720);
    unsigned* hist = (unsigned*)(ws + 1270720);
    unsigned* cnt = (unsigned*)(ws + 1287104);
    unsigned* off = (unsigned*)(ws + 1303488);
    u64* unsorted = (u64*)(ws + 1319872);

    k_init<<<dim3(16), dim3(256), 0, stream>>>(hist, cnt, meta);
    k_scores<<<dim3((NBOX + 63) / 64), dim3(64), 0, stream>>>(in, scores, hist);
    k_thresh<<<dim3(1), dim3(1024), 0, stream>>>(hist, off, meta);
    k_scatter<<<dim3((NBOX + 255) / 256), dim3(256), 0, stream>>>(scores, meta, off, cnt, unsorted);
    k_rank<<<dim3(CMAX / 256), dim3(256), 0, stream>>>(unsorted, off, hist, meta, sorted);
    k_masks<<<dim3(W64, W64), dim3(256), 0, stream>>>(in, sorted, meta, masks, validmask);
    k_sweep<<<dim3(1), dim3(64), 0, stream>>>(masks, validmask, meta, keptpos);
    k_output<<<dim3((MAXKEEP + 255) / 256), dim3(256), 0, stream>>>(in, sorted, meta, keptpos, out);
}

// Round 6
// 140.964 us; speedup vs baseline: 12.8892x; 1.0910x over previous
//
#include <hip/hip_runtime.h>

#define NBOX 300000
#define NFEAT 85
#define NCLS 80
#define NBUCK 4096
#define CMAX 8192
#define W64 (CMAX / 64)   // 128 mask words per candidate row
#define MAXKEEP 1000
#define PRE 24            // prefetched rows per block in sweep (exact-spec, cap)
#define SC_BLOCKS 256
#define SC_WPB 3
#define NTF (NBOX / 64)   // 4687 full 64-row tiles; tail 32 rows

typedef unsigned long long u64;

__device__ __forceinline__ int bucket_of(float s) {
    int b = (int)((s - 0.3f) * (4096.0f / 0.7f));
    if (b < 0) b = 0;
    if (b > NBUCK - 1) b = NBUCK - 1;
    return b;
}

__device__ __forceinline__ bool sup_iou(float by1, float bx1, float by2, float bx2, float ba,
                                        float y1, float x1, float y2, float x2, float area) {
    float iy1 = fmaxf(by1, y1), ix1 = fmaxf(bx1, x1);
    float iy2 = fminf(by2, y2), ix2 = fminf(bx2, x2);
    float inter = fmaxf(iy2 - iy1, 0.0f) * fmaxf(ix2 - ix1, 0.0f);
    float uni = ba + area - inter;
    float iou = (uni > 0.0f) ? inter / uni : 0.0f;
    return iou > 0.5f;
}

// n-th (0-based) set bit position of m; undefined if n >= popcount(m)
__device__ __forceinline__ int nth_set(u64 m, int n) {
    int pos = 0;
    int c = __popcll(m & 0xFFFFFFFFull);
    if (n >= c) { n -= c; pos = 32; m >>= 32; }
    unsigned x = (unsigned)m;
    c = __popc(x & 0xFFFFu);
    if (n >= c) { n -= c; pos += 16; x >>= 16; }
    c = __popc(x & 0xFFu);
    if (n >= c) { n -= c; pos += 8; x >>= 8; }
    c = __popc(x & 0xFu);
    if (n >= c) { n -= c; pos += 4; x >>= 4; }
    c = __popc(x & 0x3u);
    if (n >= c) { n -= c; pos += 2; x >>= 2; }
    c = x & 1u;
    if (n >= c) { pos += 1; }
    return pos;
}

__global__ void k_init(unsigned* __restrict__ hist, unsigned* __restrict__ cnt,
                       int* __restrict__ meta) {
    int i = blockIdx.x * blockDim.x + threadIdx.x;
    if (i < NBUCK) { hist[i] = 0u; cnt[i] = 0u; }
    if (i < 8) meta[i] = 0;
}

// Persistent-wave double-buffered async-DMA scores. 3 waves/block, each wave owns
// a private 2x(64 rows x 85 f32) LDS pipeline via global_load_lds; counted vmcnt
// keeps next tile's 22 loads in flight under current tile's compute. No barriers
// (per-wave DMA -> per-wave vmcnt suffices).
__global__ void __launch_bounds__(192, 1) k_scores(const float* __restrict__ in,
        float* __restrict__ scores, unsigned* __restrict__ hist) {
    __shared__ float lds[SC_WPB][2][64 * NFEAT];  // 130560 B
    int lane = threadIdx.x & 63;
    int wv = threadIdx.x >> 6;
    int gw = blockIdx.x * SC_WPB + wv;
    const int NW = SC_BLOCKS * SC_WPB;

    // prologue: issue tile gw -> buf 0 (22 DMA ops, 5440 floats)
    if (gw < NTF) {
        const float* src = in + (size_t)gw * 64 * NFEAT;
        #pragma unroll
        for (int k = 0; k < 21; ++k)
            __builtin_amdgcn_global_load_lds(
                (const __attribute__((address_space(1))) void*)(src + k * 256 + lane * 4),
                (__attribute__((address_space(3))) void*)&lds[wv][0][k * 256], 16, 0, 0);
        __builtin_amdgcn_global_load_lds(
            (const __attribute__((address_space(1))) void*)(src + 21 * 256 + lane),
            (__attribute__((address_space(3))) void*)&lds[wv][0][21 * 256], 4, 0, 0);
    }
    int buf = 0;
    bool first = true;
    for (int t = gw; t < NTF; t += NW) {
        int tn = t + NW;
        bool more = (tn < NTF);
        if (more) {  // issue next tile into the other buffer
            const float* src = in + (size_t)tn * 64 * NFEAT;
            #pragma unroll
            for (int k = 0; k < 21; ++k)
                __builtin_amdgcn_global_load_lds(
                    (const __attribute__((address_space(1))) void*)(src + k * 256 + lane * 4),
                    (__attribute__((address_space(3))) void*)&lds[wv][buf ^ 1][k * 256], 16, 0, 0);
            __builtin_amdgcn_global_load_lds(
                (const __attribute__((address_space(1))) void*)(src + 21 * 256 + lane),
                (__attribute__((address_space(3))) void*)&lds[wv][buf ^ 1][21 * 256], 4, 0, 0);
        }
        // wait for tile t's 22 loads (always the oldest outstanding ops).
        // N <= guaranteed-newer-count: first iter newer = 22 (next tile's loads);
        // steady state newer >= 22 + 1 (score store); tail: drain all.
        if (!more)      asm volatile("s_waitcnt vmcnt(0)" ::: "memory");
        else if (first) asm volatile("s_waitcnt vmcnt(22)" ::: "memory");
        else            asm volatile("s_waitcnt vmcnt(23)" ::: "memory");
        first = false;
        const float* row = &lds[wv][buf][lane * NFEAT];
        float conf = row[4];
        float mx = row[5];
        #pragma unroll
        for (int j = 6; j < NFEAT; ++j) mx = fmaxf(mx, row[j]);
        float best = conf * mx;  // == max_j(conf*p_j) exactly (conf>=0, rounding monotone)
        scores[t * 64 + lane] = best;
        if (best >= 0.3f) atomicAdd(&hist[bucket_of(best)], 1u);
        buf ^= 1;
    }
    // tail: rows NTF*64 .. NBOX-1 (32 rows), scalar path
    if (gw == 0 && lane < (NBOX - NTF * 64)) {
        const float* row = in + (size_t)(NTF * 64 + lane) * NFEAT;
        float conf = row[4];
        float mx = row[5];
        #pragma unroll
        for (int j = 6; j < NFEAT; ++j) mx = fmaxf(mx, row[j]);
        float best = conf * mx;
        scores[NTF * 64 + lane] = best;
        if (best >= 0.3f) atomicAdd(&hist[bucket_of(best)], 1u);
    }
}

// Suffix sums over buckets; bstar = smallest b with suffix(b) <= CMAX;
// off[b] = suffix(b+1); meta[0] = suffix(bstar) (deterministic top-prefix).
__global__ void __launch_bounds__(1024) k_thresh(const unsigned* __restrict__ hist,
                                                 unsigned* __restrict__ off,
                                                 int* __restrict__ meta) {
    __shared__ unsigned chunk[1024];
    int t = threadIdx.x;
    unsigned h[4];
    unsigned s = 0;
    #pragma unroll
    for (int j = 0; j < 4; ++j) { h[j] = hist[t * 4 + j]; s += h[j]; }
    chunk[t] = s;
    __syncthreads();
    for (int o = 1; o < 1024; o <<= 1) {
        unsigned add = (t + o < 1024) ? chunk[t + o] : 0u;
        __syncthreads();
        chunk[t] += add;
        __syncthreads();
    }
    unsigned after = (t + 1 < 1024) ? chunk[t + 1] : 0u;
    unsigned suf[5];
    suf[4] = after;
    #pragma unroll
    for (int j = 3; j >= 0; --j) suf[j] = suf[j + 1] + h[j];
    #pragma unroll
    for (int j = 0; j < 4; ++j) {
        int b = t * 4 + j;
        off[b] = suf[j] - h[j];
        unsigned sufb = suf[j];
        unsigned sufprev;
        if (b == 0) sufprev = 0xFFFFFFFFu;
        else if (j > 0) sufprev = suf[j - 1];
        else sufprev = sufb + hist[b - 1];
        if (sufb <= (unsigned)CMAX && sufprev > (unsigned)CMAX) {
            meta[1] = b;
            meta[0] = (int)sufb;
        }
    }
}

__global__ void k_scatter(const float* __restrict__ scores, const int* __restrict__ meta,
                          const unsigned* __restrict__ off, unsigned* __restrict__ cnt,
                          u64* __restrict__ unsorted) {
    int i = blockIdx.x * blockDim.x + threadIdx.x;
    if (i >= NBOX) return;
    float s = scores[i];
    if (s < 0.3f) return;
    int b = bucket_of(s);
    if (b < meta[1]) return;
    unsigned slot = off[b] + atomicAdd(&cnt[b], 1u);
    if (slot < CMAX)
        unsorted[slot] = ((u64)__float_as_uint(s) << 32) |
                         (u64)(0xFFFFFFFFu - (unsigned)i);
}

// Exact rank within bucket -> fully sorted, deterministic (keys unique).
// Also compacts each candidate's box into boxes4 (coalesced consumption downstream).
__global__ void k_rank(const float* __restrict__ in, const u64* __restrict__ unsorted,
                       const unsigned* __restrict__ off, const unsigned* __restrict__ hist,
                       const int* __restrict__ meta, u64* __restrict__ sorted,
                       float4* __restrict__ boxes4) {
    int i = blockIdx.x * blockDim.x + threadIdx.x;
    int total = meta[0];
    if (i >= total) return;
    u64 k = unsorted[i];
    float s = __uint_as_float((unsigned)(k >> 32));
    int b = bucket_of(s);
    unsigned base = off[b];
    unsigned n = hist[b];
    unsigned r = 0;
    for (unsigned u = 0; u < n; ++u) r += (unsorted[base + u] > k) ? 1u : 0u;
    sorted[base + r] = k;
    int bi = (int)(0xFFFFFFFFu - (unsigned)(k & 0xFFFFFFFFull));
    const float* p = in + (size_t)bi * NFEAT;
    boxes4[base + r] = make_float4(p[0], p[1], p[2], p[3]);  // y1,x1,y2,x2
}

// masks[i][w] bit b = (j = w*64+b) > i && IoU(i,j) > 0.5.  Words tj >= ti written
// (0 for invalid i/j). Diag blocks also emit validmask[ti] (bit r = row has
// positive extents; zero-extent rows provably have all-zero mask rows).
__global__ void __launch_bounds__(256) k_masks(const float4* __restrict__ boxes4,
        const int* __restrict__ meta, u64* __restrict__ masks,
        u64* __restrict__ validmask) {
    int ti = blockIdx.y, tj = blockIdx.x;
    if (tj < ti) return;
    int count = meta[0];
    if (count > CMAX) count = CMAX;
    __shared__ float4 rb[64];
    int t = threadIdx.x;
    if (t < 64) {
        int r = ti * 64 + t;
        rb[t] = (r < count) ? boxes4[r] : make_float4(0.f, 0.f, 0.f, 0.f);
    }
    int lane = t & 63, wid = t >> 6;
    int cj = tj * 64 + lane;
    bool cvalid = (cj < count);
    float4 cb = cvalid ? boxes4[cj] : make_float4(0.f, 0.f, 0.f, 0.f);
    float carea = (cb.z - cb.x) * (cb.w - cb.y);
    __syncthreads();
    if (ti == tj && t < 64) {   // wave 0 exactly: ballot is wave-wide
        float4 b = rb[t];
        bool v = (b.z > b.x) && (b.w > b.y);
        u64 vb = __ballot(v ? 1 : 0);
        if (t == 0) validmask[ti] = vb;
    }
    #pragma unroll
    for (int r = 0; r < 16; ++r) {
        int i = ti * 64 + wid * 16 + r;
        float4 b = rb[wid * 16 + r];
        float ba = (b.z - b.x) * (b.w - b.y);
        bool s = cvalid && (cj > i) && (i < count) &&
                 sup_iou(b.x, b.y, b.z, b.w, ba, cb.x, cb.y, cb.z, cb.w, carea);
        u64 word = __ballot(s ? 1 : 0);
        if (lane == 0) masks[(size_t)i * W64 + tj] = word;
    }
}

// Greedy sweep, one wave. Lane l owns R/valid words 2l, 2l+1.
// Per block w: diag word gathered one block ahead; greedy chain gated by
// Z=ballot(diag==0); row-OR uses EXACT next-block prefetch (spec = ~R & valid
// computed after R is final through w, <=PRE rows into static registers);
// degenerate (invalid) rows are provably all-zero and never loaded.
__global__ void __launch_bounds__(64) k_sweep(const u64* __restrict__ masks,
        const u64* __restrict__ validmask, int* __restrict__ meta,
        int* __restrict__ keptpos) {
    int lane = threadIdx.x;
    int count = meta[0];
    if (count > CMAX) count = CMAX;
    int nblk = (count + 63) >> 6;
    u64 r0 = 0ull, r1 = 0ull;
    u64 v0 = validmask[2 * lane], v1 = validmask[2 * lane + 1];
    int nk = 0;

    u64 pre_lo[PRE], pre_hi[PRE];
    u64 spec_cur = 0ull, diag_cur = 0ull;

    if (nblk > 0) {
        diag_cur = masks[(size_t)lane * W64];  // diag word of block 0
        int rc = count;
        u64 vm0 = (rc >= 64) ? ~0ull : ((1ull << rc) - 1ull);
        spec_cur = __shfl(v0, 0) & vm0;        // valid & surv(0)=vm
        u64 t = spec_cur;
        #pragma unroll
        for (int k = 0; k < PRE; ++k) {
            bool has = (t != 0ull);
            int b = has ? (__ffsll(t) - 1) : 0;
            t &= t - 1;
            const u64* p = masks + (size_t)b * W64 + 2 * lane;
            pre_lo[k] = p[0]; pre_hi[k] = p[1];  // dup row-0 loads when !has (L2-hit)
        }
    }

    for (int w = 0; w < nblk && nk < MAXKEEP; ++w) {
        int base = w << 6;
        int rc = count - base;
        u64 vm = (rc >= 64) ? ~0ull : ((1ull << rc) - 1ull);
        u64 rw = __shfl((w & 1) ? r1 : r0, w >> 1);
        u64 surv = ~rw & vm;

        // diag gather for w+1: issued now, consumed next iteration (fully hidden)
        u64 diag_next = 0ull;
        if (w + 1 < nblk)
            diag_next = masks[(size_t)((w + 1) * 64 + lane) * W64 + (w + 1)];

        // in-block greedy: only nonzero-diag candidates enter the serial chain
        u64 Z = __ballot(diag_cur == 0ull);
        u64 rem_l = 0ull;
        u64 mnz = surv & ~Z;
        while (mnz) {
            int b = __ffsll(mnz) - 1;
            mnz &= mnz - 1;
            if ((rem_l >> b) & 1ull) continue;
            u64 db = __shfl(diag_cur, b);
            rem_l |= db;
            mnz &= ~db;
        }
        u64 kept = surv & ~rem_l;

        // truncate to exactly MAXKEEP in index order
        int kp = __popcll(kept);
        int room = MAXKEEP - nk;
        if (kp > room) {
            while (kp > room) { kept &= ~(1ull << (63 - __clzll(kept))); --kp; }
        }
        if (lane < kp) keptpos[nk + lane] = base + nth_set(kept, lane);
        nk += kp;
        if (nk >= MAXKEEP) break;

        // OR kept&valid rows from prefetched regs (walk mirrors the issue walk)
        {
            u64 t = spec_cur;
            u64 alo = 0ull, ahi = 0ull;
            #pragma unroll
            for (int k = 0; k < PRE; ++k) {
                bool has = (t != 0ull);
                int b = has ? (__ffsll(t) - 1) : 0;
                t &= t - 1;
                bool use = has && (((kept >> b) & 1ull) != 0ull);
                alo |= use ? pre_lo[k] : 0ull;
                ahi |= use ? pre_hi[k] : 0ull;
            }
            // fallback: kept rows beyond the PRE cap (t == spec remainder)
            u64 km = kept & t;
            while (km) {
                int b = __ffsll(km) - 1;
                km &= km - 1;
                const u64* p = masks + (size_t)(base + b) * W64 + 2 * lane;
                alo |= p[0]; ahi |= p[1];
            }
            r0 |= alo; r1 |= ahi;
        }

        // prefetch rows for w+1: R final through w -> spec is EXACT surv&valid
        if (w + 1 < nblk) {
            int base2 = base + 64;
            int rc2 = count - base2;
            u64 vm2 = (rc2 >= 64) ? ~0ull : ((rc2 <= 0) ? 0ull : ((1ull << rc2) - 1ull));
            int w2 = w + 1;
            u64 rw2 = __shfl((w2 & 1) ? r1 : r0, w2 >> 1);
            u64 vw2 = __shfl((w2 & 1) ? v1 : v0, w2 >> 1);
            spec_cur = ~rw2 & vw2 & vm2;
            u64 t = spec_cur;
            #pragma unroll
            for (int k = 0; k < PRE; ++k) {
                bool has = (t != 0ull);
                int b = has ? (__ffsll(t) - 1) : 0;
                t &= t - 1;
                const u64* p = masks + (size_t)(base2 + b) * W64 + 2 * lane;
                pre_lo[k] = p[0]; pre_hi[k] = p[1];
            }
        }
        diag_cur = diag_next;
    }
    if (lane == 0) meta[2] = nk;
}

__global__ void k_output(const float* __restrict__ in, const u64* __restrict__ gkeys,
                         const int* __restrict__ meta, const int* __restrict__ keptpos,
                         float* __restrict__ out) {
    int r = blockIdx.x * blockDim.x + threadIdx.x;
    if (r >= MAXKEEP) return;
    int kc = meta[2];
    float o0 = 0.f, o1 = 0.f, o2 = 0.f, o3 = 0.f, o4 = 0.f, o5 = 0.f;
    if (r < kc) {
        int pos = keptpos[r];
        u64 key = gkeys[pos];
        int bi = (int)(0xFFFFFFFFu - (unsigned)(key & 0xFFFFFFFFull));
        const float* row = in + (size_t)bi * NFEAT;
        o0 = row[0]; o1 = row[1]; o2 = row[2]; o3 = row[3];
        float conf = row[4];
        float best = -1.0f;
        int cls = 0;
        for (int j = 0; j < NCLS; ++j) {
            float s = conf * row[5 + j];
            if (s > best) { best = s; cls = j; }  // strict > : first occurrence = jnp.argmax
        }
        o4 = (float)cls; o5 = best;
    }
    float* orow = out + r * 6;
    orow[0] = o0; orow[1] = o1; orow[2] = o2;
    orow[3] = o3; orow[4] = o4; orow[5] = o5;
}

extern "C" void kernel_launch(void* const* d_in, const int* in_sizes, int n_in,
                              void* d_out, int out_size, void* d_ws, size_t ws_size,
                              hipStream_t stream) {
    const float* in = (const float*)d_in[0];
    float* out = (float*)d_out;
    char* ws = (char*)d_ws;
    // ws layout (bytes). masks OVERLAYS sort-phase scratch (dead before k_masks).
    //   [0, 65536)              sorted    u64[8192]
    //   [65536, 65600)          meta      i32[8]  {0:total, 1:bstar, 2:kept count}
    //   [65600, 69696)          keptpos   i32[1024]
    //   [69696, 70720)          validmask u64[128]
    //   [70720, 201792)         boxes4    float4[8192]
    //   [201792, 8590400)       masks     u64[8192*128]  (8 MB), overlaying:
    //     [201792, 1401792)       scores   f32[300000]
    //     [1401792, 1418176)      hist     u32[4096]
    //     [1418176, 1434560)      cnt      u32[4096]
    //     [1434560, 1450944)      off      u32[4096]
    //     [1450944, 1516480)      unsorted u64[8192]
    u64* sorted = (u64*)(ws);
    int* meta = (int*)(ws + 65536);
    int* keptpos = (int*)(ws + 65600);
    u64* validmask = (u64*)(ws + 69696);
    float4* boxes4 = (float4*)(ws + 70720);
    u64* masks = (u64*)(ws + 201792);
    float* scores = (float*)(ws + 201792);
    unsigned* hist = (unsigned*)(ws + 1401792);
    unsigned* cnt = (unsigned*)(ws + 1418176);
    unsigned* off = (unsigned*)(ws + 1434560);
    u64* unsorted = (u64*)(ws + 1450944);

    k_init<<<dim3(16), dim3(256), 0, stream>>>(hist, cnt, meta);
    k_scores<<<dim3(SC_BLOCKS), dim3(192), 0, stream>>>(in, scores, hist);
    k_thresh<<<dim3(1), dim3(1024), 0, stream>>>(hist, off, meta);
    k_scatter<<<dim3((NBOX + 255) / 256), dim3(256), 0, stream>>>(scores, meta, off, cnt, unsorted);
    k_rank<<<dim3(CMAX / 256), dim3(256), 0, stream>>>(in, unsorted, off, hist, meta, sorted, boxes4);
    k_masks<<<dim3(W64, W64), dim3(256), 0, stream>>>(boxes4, meta, masks, validmask);
    k_sweep<<<dim3(1), dim3(64), 0, stream>>>(masks, validmask, meta, keptpos);
    k_output<<<dim3((MAXKEEP + 255) / 256), dim3(256), 0, stream>>>(in, sorted, meta, keptpos, out);
}